// Round 1
// baseline (163.419 us; speedup 1.0000x reference)
//
#include <hip/hip_runtime.h>
#include <cstdint>
#include <cmath>

#define B_ 2
#define L_ 1024
#define D_ 256
#define U_ 32
#define ROWS_ 2048   // B_*L_
#define WBSTR 65     // LDS weight tile row stride (floats): 65*4B -> bank+1/row, 2-way max
#define PSTR 1032    // LDS P row stride (halfwords): 2064B, 16B-aligned

typedef __attribute__((ext_vector_type(8))) short short8;
typedef __attribute__((ext_vector_type(4))) float floatx4;

// ---- workspace layout (bytes) ------------------------------------------------
// P holds EXP2 of the scaled logits: rows 0-31: equ = exp2(SC*(q·Wt+bh));
// rows 32-63: ekk = exp2(SC*(k·Wx)).  exp2(qu+kk) == equ*ekk (hoisted).
#define OFF_P  0u                      // [64][2048] f32 = 512 KB
#define OFF_XT (OFF_P + 524288u)       // [B][D][L] bf16 = 1 MB
#define OFF_WV (OFF_XT + 1048576u)     // [32] f32 = 128 B  (-2*Wa)

__device__ __forceinline__ float bf2f(unsigned short u) {
    union { unsigned int i; float f; } v; v.i = ((unsigned int)u) << 16; return v.f;
}
__device__ __forceinline__ unsigned short f2bf(float f) {
    union { float f; unsigned int i; } v; v.f = f;
    unsigned int r = v.i + 0x7FFFu + ((v.i >> 16) & 1u);
    return (unsigned short)(r >> 16);
}

// Inline dtype sniff (per wave). Little-endian: for fp32 data the EVEN ushorts
// are low mantissa halves (garbage exponents); for bf16 data they are genuine.
// Returns 1 = fp32, 0 = bf16.
__device__ __forceinline__ int sniff_is_f32(const void* x) {
    const unsigned short* xu = (const unsigned short*)x;
    float f = bf2f(xu[2 * (threadIdx.x & 63)]);
    bool plausible = (f == f) && (fabsf(f) < 1e4f) && (fabsf(f) > 1e-10f);
    unsigned long long m = __ballot(plausible);
    return (__popcll(m) >= 60) ? 0 : 1;
}

// ---------------------------------------------------------------------------
// K1 proj_all (REDESIGNED): 256 blocks x 512 thr, pure VALU (67 MFLOP job --
// MFMA machinery was pure overhead; previous 64-block grid used <=25% of CUs).
//   wave w (0..7) = row n0+w; lane = unit u' (0..31 -> Wt/q, 32..63 -> Wx/k).
//   1. stage weights -> WB[d][u'] f32, stride-65 rows (conflict-free).
//   2. stage x row   -> XR[w][256] f32 (one float4 per lane).
//   3. dot over d: ds_read_b128 broadcast of x + stride-row WB reads, 4 accs.
//   4. exp2 of scaled logit -> PL LDS -> coalesced 32B P stores.
//   5. xT bf16 transpose store straight from XR.
// Block 0 also precomputes WV[u] = -2*Wa[u].
// ---------------------------------------------------------------------------
__global__ __launch_bounds__(512) void proj_all(const void* __restrict__ x,  const void* __restrict__ Wt,
                         const void* __restrict__ Wx, const void* __restrict__ bh,
                         const void* __restrict__ Wa,
                         float* __restrict__ P, unsigned short* __restrict__ xT,
                         float* __restrict__ WV) {
    const int t = threadIdx.x;
    const int isf32 = sniff_is_f32(x);
    const int n0 = blockIdx.x * 8;           // 8 rows per block
    const int b  = n0 >> 10;
    const int l0 = n0 & (L_ - 1);
    __shared__ float WB[256 * WBSTR];        // 66.6 KB weights f32
    __shared__ float XR[8 * 256];            // 8 KB x rows f32
    __shared__ float PL[64 * 9];             // 2.25 KB logit staging

    if (blockIdx.x == 0 && t < U_) {
        float wav = isf32 ? ((const float*)Wa)[t] : bf2f(((const unsigned short*)Wa)[t]);
        WV[t] = -2.0f * wav;
    }

    // Wt is [D][32] (d-major): i = d*32+u  ->  WB[d][u].  Writes consecutive -> free.
    #pragma unroll
    for (int j = 0; j < 16; ++j) {
        const int i = t + 512 * j;
        float v = isf32 ? ((const float*)Wt)[i] : bf2f(((const unsigned short*)Wt)[i]);
        WB[(i >> 5) * WBSTR + (i & 31)] = v;
    }
    // Wx is [32][256] (u-major): e = u*256+d -> WB[d][32+u]. Stride-65 rows ->
    // consecutive d -> bank+1 -> 2-way max (free).
    #pragma unroll
    for (int j = 0; j < 16; ++j) {
        const int e = t + 512 * j;
        float v = isf32 ? ((const float*)Wx)[e] : bf2f(((const unsigned short*)Wx)[e]);
        WB[(e & 255) * WBSTR + 32 + (e >> 8)] = v;
    }

    const int w    = t >> 6;
    const int lane = t & 63;
    const int row  = n0 + w;

    if (isf32) {
        float4 xv = *((const float4*)x + (size_t)row * (D_ / 4) + lane);
        *(float4*)(XR + w * 256 + 4 * lane) = xv;
    } else {
        const unsigned short* xs = (const unsigned short*)x + (size_t)row * D_ + 4 * lane;
        float4 xv; xv.x = bf2f(xs[0]); xv.y = bf2f(xs[1]); xv.z = bf2f(xs[2]); xv.w = bf2f(xs[3]);
        *(float4*)(XR + w * 256 + 4 * lane) = xv;
    }
    __syncthreads();

    // ---- dot product: lane u' over d (wave-uniform x broadcast reads)
    float a0 = 0.f, a1 = 0.f, a2 = 0.f, a3 = 0.f;
    const float* wbp = WB + lane;
    const float* xr  = XR + w * 256;
    #pragma unroll
    for (int d = 0; d < D_; d += 4) {
        float4 xv = *(const float4*)(xr + d);
        a0 = fmaf(wbp[(d + 0) * WBSTR], xv.x, a0);
        a1 = fmaf(wbp[(d + 1) * WBSTR], xv.y, a1);
        a2 = fmaf(wbp[(d + 2) * WBSTR], xv.z, a2);
        a3 = fmaf(wbp[(d + 3) * WBSTR], xv.w, a3);
    }
    float dotv = (a0 + a1) + (a2 + a3);

    float bhv = 0.f;
    if (lane < U_)   // bh applies to q-units only (matches reference)
        bhv = isf32 ? ((const float*)bh)[lane] : bf2f(((const unsigned short*)bh)[lane]);

    const float SC = 2.0f * 1.4426950408889634f;   // 2*log2(e)
    PL[lane * 9 + w] = __builtin_amdgcn_exp2f(SC * (dotv + bhv));
    __syncthreads();

    // ---- P store: 512 threads = 64 units x 8 rows, 32B contiguous per unit
    {
        const int u = t >> 3, r = t & 7;
        P[(size_t)u * ROWS_ + n0 + r] = PL[u * 9 + r];
    }

    // ---- xT store: thread t<256 packs 8 rows of column d into one 16B store
    if (t < 256) {
        const int d = t;
        union { short8 s; unsigned short h[8]; } o;
        #pragma unroll
        for (int r = 0; r < 8; ++r) o.h[r] = f2bf(XR[r * 256 + d]);
        *(short8*)(xT + (size_t)b * (D_ * L_) + (size_t)d * L_ + l0) = o.s;
    }
}

// ---------------------------------------------------------------------------
// K2 alpha_pv: FUSED alpha+softmax+PV. 256 blocks x 512 thr (8 waves).
// Phase 1 (u-OUTER): equ/wu now PRELOADED lane-parallel before the loop and
// broadcast via __shfl -- removes the 32-long dependent uniform-load chain.
// unroll 4 for more key-loads in flight.
//   alpha_eff[key] = sum_u wu * rcp(equ*ekk + 1)   (wu = -2*Wa[u]; consts
//   dropped -- softmax invariant; exp2 pre-hoisted into P by proj_all).
// Wave softmax; normalized bf16 row -> LDS Pl[w][*] (A-frag layout).
// Phase 2: PV via MFMA 16x16x32: A = Pl rows, B = xT d-slice (wave w -> d-slice).
// ---------------------------------------------------------------------------
__global__ __launch_bounds__(512) void alpha_pv(const float* __restrict__ P,
                                                const float* __restrict__ WV,
                                                const void* __restrict__ x,
                                                const unsigned short* __restrict__ xT,
                                                void* __restrict__ out) {
    const int w    = threadIdx.x >> 6;       // 0..7
    const int lane = threadIdx.x & 63;
    const int row  = blockIdx.x * 8 + w;     // global row = b*L + qi
    const int b    = row >> 10;
    const int isf32 = sniff_is_f32(x);
    __shared__ unsigned short Pl[16 * PSTR];   // 33 KB

    // ---- phase 1: alpha + softmax (u-outer; lane holds keys jj*256+4*lane+c)
    const float* Pq = P + row;                              // equ: stride ROWS_ per u
    const float* kb = P + (size_t)32 * ROWS_ + (size_t)b * L_ + 4 * lane;

    // preload all equ/wu (lanes 0..31 gather; broadcast by shfl inside loop)
    float eq_l = 0.f, wu_l = 0.f;
    if (lane < U_) {
        eq_l = Pq[(size_t)lane * ROWS_];
        wu_l = WV[lane];
    }

    float alp[16];
    #pragma unroll
    for (int j = 0; j < 16; ++j) alp[j] = 0.f;

    #pragma unroll 4
    for (int u = 0; u < U_; ++u) {
        const float equ = __shfl(eq_l, u, 64);
        const float wu  = __shfl(wu_l, u, 64);
        const float* kr = kb + (size_t)u * ROWS_;
        float4 k0 = *(const float4*)(kr);
        float4 k1 = *(const float4*)(kr + 256);
        float4 k2 = *(const float4*)(kr + 512);
        float4 k3 = *(const float4*)(kr + 768);
        alp[0]  = fmaf(wu, __builtin_amdgcn_rcpf(fmaf(equ, k0.x, 1.f)), alp[0]);
        alp[1]  = fmaf(wu, __builtin_amdgcn_rcpf(fmaf(equ, k0.y, 1.f)), alp[1]);
        alp[2]  = fmaf(wu, __builtin_amdgcn_rcpf(fmaf(equ, k0.z, 1.f)), alp[2]);
        alp[3]  = fmaf(wu, __builtin_amdgcn_rcpf(fmaf(equ, k0.w, 1.f)), alp[3]);
        alp[4]  = fmaf(wu, __builtin_amdgcn_rcpf(fmaf(equ, k1.x, 1.f)), alp[4]);
        alp[5]  = fmaf(wu, __builtin_amdgcn_rcpf(fmaf(equ, k1.y, 1.f)), alp[5]);
        alp[6]  = fmaf(wu, __builtin_amdgcn_rcpf(fmaf(equ, k1.z, 1.f)), alp[6]);
        alp[7]  = fmaf(wu, __builtin_amdgcn_rcpf(fmaf(equ, k1.w, 1.f)), alp[7]);
        alp[8]  = fmaf(wu, __builtin_amdgcn_rcpf(fmaf(equ, k2.x, 1.f)), alp[8]);
        alp[9]  = fmaf(wu, __builtin_amdgcn_rcpf(fmaf(equ, k2.y, 1.f)), alp[9]);
        alp[10] = fmaf(wu, __builtin_amdgcn_rcpf(fmaf(equ, k2.z, 1.f)), alp[10]);
        alp[11] = fmaf(wu, __builtin_amdgcn_rcpf(fmaf(equ, k2.w, 1.f)), alp[11]);
        alp[12] = fmaf(wu, __builtin_amdgcn_rcpf(fmaf(equ, k3.x, 1.f)), alp[12]);
        alp[13] = fmaf(wu, __builtin_amdgcn_rcpf(fmaf(equ, k3.y, 1.f)), alp[13]);
        alp[14] = fmaf(wu, __builtin_amdgcn_rcpf(fmaf(equ, k3.z, 1.f)), alp[14]);
        alp[15] = fmaf(wu, __builtin_amdgcn_rcpf(fmaf(equ, k3.w, 1.f)), alp[15]);
    }

    float amax = alp[0];
    #pragma unroll
    for (int j = 1; j < 16; ++j) amax = fmaxf(amax, alp[j]);
    #pragma unroll
    for (int off = 32; off > 0; off >>= 1) amax = fmaxf(amax, __shfl_xor(amax, off, 64));

    const float L2E = 1.4426950408889634f;
    float s = 0.f;
    #pragma unroll
    for (int j = 0; j < 16; ++j) {
        alp[j] = __builtin_amdgcn_exp2f((alp[j] - amax) * L2E);
        s += alp[j];
    }
    #pragma unroll
    for (int off = 32; off > 0; off >>= 1) s += __shfl_xor(s, off, 64);
    const float rinv = __builtin_amdgcn_rcpf(s);

    #pragma unroll
    for (int jj = 0; jj < 4; ++jj) {
        ushort4 pk;
        pk.x = f2bf(alp[4*jj+0] * rinv);
        pk.y = f2bf(alp[4*jj+1] * rinv);
        pk.z = f2bf(alp[4*jj+2] * rinv);
        pk.w = f2bf(alp[4*jj+3] * rinv);
        *(ushort4*)(Pl + w * PSTR + jj * 256 + 4 * lane) = pk;   // key = jj*256+4*lane+c
    }
    __syncthreads();

    // ---- phase 2: PV.  wave w -> d-slice [32w, 32w+32)
    const int m  = lane & 15;
    const int ko = (lane >> 4) * 8;
    const int d0 = w * 32;
    const unsigned short* xb0 = xT + (size_t)b * (D_ * L_) + (size_t)(d0 + m) * L_ + ko;
    const unsigned short* xb1 = xb0 + (size_t)16 * L_;
    const unsigned short* pp  = Pl + (size_t)m * PSTR + ko;

    floatx4 acc0 = {0,0,0,0}, acc1 = {0,0,0,0};
    short8 pa = *(const short8*)(pp);
    short8 x0 = *(const short8*)(xb0);
    short8 x1 = *(const short8*)(xb1);
    for (int ks = 32; ks < L_; ks += 32) {
        short8 npa = *(const short8*)(pp + ks);
        short8 nx0 = *(const short8*)(xb0 + ks);
        short8 nx1 = *(const short8*)(xb1 + ks);
        acc0 = __builtin_amdgcn_mfma_f32_16x16x32_bf16(pa, x0, acc0, 0, 0, 0);
        acc1 = __builtin_amdgcn_mfma_f32_16x16x32_bf16(pa, x1, acc1, 0, 0, 0);
        pa = npa; x0 = nx0; x1 = nx1;
    }
    acc0 = __builtin_amdgcn_mfma_f32_16x16x32_bf16(pa, x0, acc0, 0, 0, 0);
    acc1 = __builtin_amdgcn_mfma_f32_16x16x32_bf16(pa, x1, acc1, 0, 0, 0);

    // C/D layout: col = lane&15 (= d offset), row = (lane>>4)*4 + reg (= q)
    const int col = lane & 15;
    const int rb  = (lane >> 4) * 4;
    const int qi0 = (blockIdx.x * 8) & (L_ - 1);   // LOCAL q index (mask out batch)
    const size_t obase = (size_t)b * (L_ * D_) + (size_t)qi0 * D_;
    if (rb < 8) {   // lanes 0-31 hold valid q-rows 0-7
        if (isf32) {
            float* ob = (float*)out + obase;
            #pragma unroll
            for (int r = 0; r < 4; ++r) {
                ob[(size_t)(rb + r) * D_ + d0 + col]      = acc0[r];
                ob[(size_t)(rb + r) * D_ + d0 + 16 + col] = acc1[r];
            }
        } else {
            unsigned short* ob = (unsigned short*)out + obase;
            #pragma unroll
            for (int r = 0; r < 4; ++r) {
                ob[(size_t)(rb + r) * D_ + d0 + col]      = f2bf(acc0[r]);
                ob[(size_t)(rb + r) * D_ + d0 + 16 + col] = f2bf(acc1[r]);
            }
        }
    }
}

extern "C" void kernel_launch(void* const* d_in, const int* in_sizes, int n_in,
                              void* d_out, int out_size, void* d_ws, size_t ws_size,
                              hipStream_t stream) {
    const void* x  = d_in[0];   // [B,L,D]  dtype sniffed at runtime (fp32 expected)
    const void* Wt = d_in[1];   // [D,U]
    const void* Wx = d_in[2];   // [U,D]
    const void* bh = d_in[3];   // [U]
    const void* Wa = d_in[4];   // [U,1]
    // d_in[5] = ba: constant pre-softmax shift -> mathematically irrelevant.

    char* ws = (char*)d_ws;
    float*          P   = (float*)(ws + OFF_P);
    unsigned short* xT  = (unsigned short*)(ws + OFF_XT);
    float*          WV  = (float*)(ws + OFF_WV);

    proj_all<<<ROWS_ / 8, 512, 0, stream>>>(x, Wt, Wx, bh, Wa, P, xT, WV);
    alpha_pv<<<ROWS_ / 8, 512, 0, stream>>>(P, WV, x, xT, d_out);
}

// Round 2
// 112.627 us; speedup vs baseline: 1.4510x; 1.4510x over previous
//
#include <hip/hip_runtime.h>
#include <cstdint>
#include <cmath>

#define B_ 2
#define L_ 1024
#define D_ 256
#define U_ 32
#define ROWS_ 2048   // B_*L_
#define WBS 280      // LDS wb row stride (halfwords): 560B, 16B-aligned
#define PSTR 1032    // LDS P row stride (halfwords): 2064B, 16B-aligned

typedef __attribute__((ext_vector_type(8))) short short8;
typedef __attribute__((ext_vector_type(4))) float floatx4;

// ---- workspace layout (bytes) ------------------------------------------------
// P holds EXP2 of the scaled logits: rows 0-31: equ = exp2(SC*(q·Wt+bh));
// rows 32-63: ekk = exp2(SC*(k·Wx)).  exp2(qu+kk) == equ*ekk (hoisted).
#define OFF_P  0u                      // [64][2048] f32 = 512 KB
#define OFF_XT (OFF_P + 524288u)       // [B][D][L] bf16 = 1 MB
#define OFF_WV (OFF_XT + 1048576u)     // [32] f32 = 128 B  (-2*Wa)

__device__ __forceinline__ float bf2f(unsigned short u) {
    union { unsigned int i; float f; } v; v.i = ((unsigned int)u) << 16; return v.f;
}
__device__ __forceinline__ unsigned short f2bf(float f) {
    union { float f; unsigned int i; } v; v.f = f;
    unsigned int r = v.i + 0x7FFFu + ((v.i >> 16) & 1u);
    return (unsigned short)(r >> 16);
}
__device__ __forceinline__ unsigned int pack_bf(float a, float b) {
    union { float f; unsigned int i; } ua, ub; ua.f = a; ub.f = b;
    unsigned int ra = ua.i + 0x7FFFu + ((ua.i >> 16) & 1u);
    unsigned int rb = ub.i + 0x7FFFu + ((ub.i >> 16) & 1u);
    return (ra >> 16) | (rb & 0xFFFF0000u);
}

// Inline dtype sniff (per wave). Returns 1 = fp32, 0 = bf16.
__device__ __forceinline__ int sniff_is_f32(const void* x) {
    const unsigned short* xu = (const unsigned short*)x;
    float f = bf2f(xu[2 * (threadIdx.x & 63)]);
    bool plausible = (f == f) && (fabsf(f) < 1e4f) && (fabsf(f) > 1e-10f);
    unsigned long long m = __ballot(plausible);
    return (__popcll(m) >= 60) ? 0 : 1;
}

// convert 8 consecutive f32 -> short8 bf16 (RNE)
__device__ __forceinline__ short8 cvt8(const float* p) {
    float4 fa = *(const float4*)p;
    float4 fb = *(const float4*)(p + 4);
    union { short8 s; unsigned int u[4]; } r;
    r.u[0] = pack_bf(fa.x, fa.y);
    r.u[1] = pack_bf(fa.z, fa.w);
    r.u[2] = pack_bf(fb.x, fb.y);
    r.u[3] = pack_bf(fb.z, fb.w);
    return r.s;
}

// ---------------------------------------------------------------------------
// K1 proj_all (ROUND-0 VERSION, reverted): per block (64 blocks x 256 thr =
// 4 waves), rows n0..n0+31:
//   1. stage Wt^T and Wx into LDS wb[64][WBS] bf16 (A-operand layout).
//   2. wave (mt, rh) computes logits via MFMA 16x16x32; B-frags = x rows
//      (read once). mt=0 waves deposit B-frags into xtile.
//   3. P stores EXP2 of the scaled logits.
//   4. coalesced uint stores of xtile -> xT[b][d][l].
// Block 0 also precomputes WV[u] = -2*Wa[u] (f32).
// [R1 post-mortem: the 256-block pure-VALU redesign was 3x SLOWER -- 75.5 KB
//  LDS/block + per-block 64 KB weight restage -> FETCH 68 MB, VALUBusy 2.2%.]
// ---------------------------------------------------------------------------
__global__ void proj_all(const void* __restrict__ x,  const void* __restrict__ Wt,
                         const void* __restrict__ Wx, const void* __restrict__ bh,
                         const void* __restrict__ Wa,
                         float* __restrict__ P, unsigned short* __restrict__ xT,
                         float* __restrict__ WV) {
    const int t = threadIdx.x;
    const int isf32 = sniff_is_f32(x);
    const int n0 = blockIdx.x * 32;
    const int b  = n0 >> 10;
    const int l0 = n0 & (L_ - 1);
    __shared__ unsigned short wb[64 * WBS];      // 35.0 KB
    __shared__ unsigned short xtile[D_ * 34];    // 17.0 KB

    if (blockIdx.x == 0 && t < U_) {
        float wav = isf32 ? ((const float*)Wa)[t] : bf2f(((const unsigned short*)Wa)[t]);
        WV[t] = -2.0f * wav;
    }

    for (int j = 0; j < 32; ++j) {
        const int i = t + 256 * j;               // i = d*32 + u
        unsigned short v = isf32 ? f2bf(((const float*)Wt)[i])
                                 : ((const unsigned short*)Wt)[i];
        wb[(i & 31) * WBS + (i >> 5)] = v;
    }
    for (int j = 0; j < 32; ++j) {
        const int e = t + 256 * j;               // e = u*256 + d
        unsigned short v = isf32 ? f2bf(((const float*)Wx)[e])
                                 : ((const unsigned short*)Wx)[e];
        wb[(32 + (e >> 8)) * WBS + (e & 255)] = v;
    }
    __syncthreads();

    const int w    = t >> 6;
    const int lane = t & 63;
    const int mt   = w & 1;         // 0 -> units 0-31 (q), 1 -> units 32-63 (k)
    const int rh   = w >> 1;
    const int m    = lane & 15;
    const int kho  = lane >> 4;
    const int u0   = mt * 32;
    const int row  = n0 + 16 * rh + m;

    floatx4 acc0 = {0,0,0,0}, acc1 = {0,0,0,0};
    #pragma unroll
    for (int k0 = 0; k0 < D_; k0 += 32) {
        const int ks = k0 + kho * 8;
        short8 a0 = *(const short8*)(wb + (u0 + m) * WBS + ks);
        short8 a1 = *(const short8*)(wb + (u0 + 16 + m) * WBS + ks);
        short8 b0;
        if (isf32) b0 = cvt8((const float*)x + (size_t)row * D_ + ks);
        else       b0 = *(const short8*)((const unsigned short*)x + (size_t)row * D_ + ks);
        acc0 = __builtin_amdgcn_mfma_f32_16x16x32_bf16(a0, b0, acc0, 0, 0, 0);
        acc1 = __builtin_amdgcn_mfma_f32_16x16x32_bf16(a1, b0, acc1, 0, 0, 0);
        if (mt == 0) {
            union { short8 s; unsigned short h[8]; } uu; uu.s = b0;
            #pragma unroll
            for (int jj = 0; jj < 8; ++jj)
                xtile[(ks + jj) * 34 + 16 * rh + m] = uu.h[jj];
        }
    }

    const float SC = 2.0f * 1.4426950408889634f;   // 2*log2(e)
    const int col = lane & 15;
    const int rb  = (lane >> 4) * 4;
    #pragma unroll
    for (int r = 0; r < 4; ++r) {
        const int ua = u0 + rb + r, ub_ = u0 + 16 + rb + r;
        float bh0 = 0.f, bh1 = 0.f;
        if (mt == 0) {
            bh0 = isf32 ? ((const float*)bh)[rb + r]      : bf2f(((const unsigned short*)bh)[rb + r]);
            bh1 = isf32 ? ((const float*)bh)[16 + rb + r] : bf2f(((const unsigned short*)bh)[16 + rb + r]);
        }
        P[(size_t)ua  * ROWS_ + n0 + 16 * rh + col] = __builtin_amdgcn_exp2f(SC * (acc0[r] + bh0));
        P[(size_t)ub_ * ROWS_ + n0 + 16 * rh + col] = __builtin_amdgcn_exp2f(SC * (acc1[r] + bh1));
    }

    __syncthreads();
    unsigned short* xtb = xT + (size_t)b * (D_ * L_) + l0;
    #pragma unroll
    for (int i = 0; i < 16; ++i) {
        const int idx = t + 256 * i;             // idx = d*16 + wq
        const int d = idx >> 4, wq = idx & 15;
        unsigned int p = *(const unsigned int*)(xtile + d * 34 + 2 * wq);
        *(unsigned int*)(xtb + (size_t)d * L_ + 2 * wq) = p;
    }
}

// ---------------------------------------------------------------------------
// K2 alpha_pv: FUSED alpha+softmax+PV. 256 blocks x 512 thr (8 waves).
// NEW (R2): ekk rows staged in LDS (f32, two 64 KB halves of 16 u each) --
// phase 1 previously re-read the full 128 KB ekk array from L2 per q-row
// (256 MB aggregate, latency-exposed at 2 waves/SIMD). Now each block reads
// ekk once from L2 (128 KB) and phase 1 streams from LDS.
//   alpha_eff[key] = sum_u wu * rcp(equ*ekk + 1)   (wu = -2*Wa[u]; consts
//   dropped -- softmax invariant; exp2 pre-hoisted into P by proj_all).
// Wave softmax; normalized bf16 row -> LDS Pl[w][*] (A-frag layout, 8 rows;
// phase-2 A rows 8-15 alias rows 0-7 -- their outputs are never stored).
// Phase 2: PV via MFMA 16x16x32: A = Pl rows, B = xT d-slice (wave w -> d).
// LDS: EK 64 KB + Pl 16.5 KB = 80.5 KB.
// ---------------------------------------------------------------------------
__global__ __launch_bounds__(512) void alpha_pv(const float* __restrict__ P,
                                                const float* __restrict__ WV,
                                                const void* __restrict__ x,
                                                const unsigned short* __restrict__ xT,
                                                void* __restrict__ out) {
    const int t    = threadIdx.x;
    const int w    = t >> 6;                 // 0..7
    const int lane = t & 63;
    const int row  = blockIdx.x * 8 + w;     // global row = b*L + qi
    const int b    = row >> 10;
    const int isf32 = sniff_is_f32(x);
    __shared__ float EK[16 * 1024];            // 64 KB: one 16-u half of ekk
    __shared__ unsigned short Pl[8 * PSTR];    // 16.5 KB

    const float* Pq  = P + row;                             // equ: stride ROWS_ per u
    const float* ekg = P + (size_t)32 * ROWS_ + (size_t)b * L_;

    // preload all equ/wu (lanes 0..31 gather; broadcast by shfl inside loop)
    float eq_l = 0.f, wu_l = 0.f;
    if (lane < U_) {
        eq_l = Pq[(size_t)lane * ROWS_];
        wu_l = WV[lane];
    }

    float alp[16];
    #pragma unroll
    for (int j = 0; j < 16; ++j) alp[j] = 0.f;

    // ---- phase 1: two halves of 16 u-rows; stage -> LDS -> accumulate
    for (int h = 0; h < 2; ++h) {
        __syncthreads();                       // all waves done with prev EK
        #pragma unroll
        for (int j = 0; j < 8; ++j) {
            const int idx = t + 512 * j;       // float4 idx: ul = idx>>8, k4 = idx&255
            const int ul = idx >> 8, k4 = idx & 255;
            float4 v = *(const float4*)(ekg + (size_t)(16 * h + ul) * ROWS_ + 4 * k4);
            *(float4*)(EK + ul * 1024 + 4 * k4) = v;
        }
        __syncthreads();

        #pragma unroll 4
        for (int ul = 0; ul < 16; ++ul) {
            const int u = 16 * h + ul;
            const float equ = __shfl(eq_l, u, 64);
            const float wu  = __shfl(wu_l, u, 64);
            const float* kr = EK + ul * 1024 + 4 * lane;
            float4 k0 = *(const float4*)(kr);
            float4 k1 = *(const float4*)(kr + 256);
            float4 k2 = *(const float4*)(kr + 512);
            float4 k3 = *(const float4*)(kr + 768);
            alp[0]  = fmaf(wu, __builtin_amdgcn_rcpf(fmaf(equ, k0.x, 1.f)), alp[0]);
            alp[1]  = fmaf(wu, __builtin_amdgcn_rcpf(fmaf(equ, k0.y, 1.f)), alp[1]);
            alp[2]  = fmaf(wu, __builtin_amdgcn_rcpf(fmaf(equ, k0.z, 1.f)), alp[2]);
            alp[3]  = fmaf(wu, __builtin_amdgcn_rcpf(fmaf(equ, k0.w, 1.f)), alp[3]);
            alp[4]  = fmaf(wu, __builtin_amdgcn_rcpf(fmaf(equ, k1.x, 1.f)), alp[4]);
            alp[5]  = fmaf(wu, __builtin_amdgcn_rcpf(fmaf(equ, k1.y, 1.f)), alp[5]);
            alp[6]  = fmaf(wu, __builtin_amdgcn_rcpf(fmaf(equ, k1.z, 1.f)), alp[6]);
            alp[7]  = fmaf(wu, __builtin_amdgcn_rcpf(fmaf(equ, k1.w, 1.f)), alp[7]);
            alp[8]  = fmaf(wu, __builtin_amdgcn_rcpf(fmaf(equ, k2.x, 1.f)), alp[8]);
            alp[9]  = fmaf(wu, __builtin_amdgcn_rcpf(fmaf(equ, k2.y, 1.f)), alp[9]);
            alp[10] = fmaf(wu, __builtin_amdgcn_rcpf(fmaf(equ, k2.z, 1.f)), alp[10]);
            alp[11] = fmaf(wu, __builtin_amdgcn_rcpf(fmaf(equ, k2.w, 1.f)), alp[11]);
            alp[12] = fmaf(wu, __builtin_amdgcn_rcpf(fmaf(equ, k3.x, 1.f)), alp[12]);
            alp[13] = fmaf(wu, __builtin_amdgcn_rcpf(fmaf(equ, k3.y, 1.f)), alp[13]);
            alp[14] = fmaf(wu, __builtin_amdgcn_rcpf(fmaf(equ, k3.z, 1.f)), alp[14]);
            alp[15] = fmaf(wu, __builtin_amdgcn_rcpf(fmaf(equ, k3.w, 1.f)), alp[15]);
        }
    }

    float amax = alp[0];
    #pragma unroll
    for (int j = 1; j < 16; ++j) amax = fmaxf(amax, alp[j]);
    #pragma unroll
    for (int off = 32; off > 0; off >>= 1) amax = fmaxf(amax, __shfl_xor(amax, off, 64));

    const float L2E = 1.4426950408889634f;
    float s = 0.f;
    #pragma unroll
    for (int j = 0; j < 16; ++j) {
        alp[j] = __builtin_amdgcn_exp2f((alp[j] - amax) * L2E);
        s += alp[j];
    }
    #pragma unroll
    for (int off = 32; off > 0; off >>= 1) s += __shfl_xor(s, off, 64);
    const float rinv = __builtin_amdgcn_rcpf(s);

    #pragma unroll
    for (int jj = 0; jj < 4; ++jj) {
        ushort4 pk;
        pk.x = f2bf(alp[4*jj+0] * rinv);
        pk.y = f2bf(alp[4*jj+1] * rinv);
        pk.z = f2bf(alp[4*jj+2] * rinv);
        pk.w = f2bf(alp[4*jj+3] * rinv);
        *(ushort4*)(Pl + w * PSTR + jj * 256 + 4 * lane) = pk;   // key = jj*256+4*lane+c
    }
    __syncthreads();

    // ---- phase 2: PV.  wave w -> d-slice [32w, 32w+32)
    const int m  = lane & 15;
    const int ko = (lane >> 4) * 8;
    const int d0 = w * 32;
    const unsigned short* xb0 = xT + (size_t)b * (D_ * L_) + (size_t)(d0 + m) * L_ + ko;
    const unsigned short* xb1 = xb0 + (size_t)16 * L_;
    const unsigned short* pp  = Pl + (size_t)(m & 7) * PSTR + ko;  // rows 8-15 alias 0-7

    floatx4 acc0 = {0,0,0,0}, acc1 = {0,0,0,0};
    short8 pa = *(const short8*)(pp);
    short8 x0 = *(const short8*)(xb0);
    short8 x1 = *(const short8*)(xb1);
    for (int ks = 32; ks < L_; ks += 32) {
        short8 npa = *(const short8*)(pp + ks);
        short8 nx0 = *(const short8*)(xb0 + ks);
        short8 nx1 = *(const short8*)(xb1 + ks);
        acc0 = __builtin_amdgcn_mfma_f32_16x16x32_bf16(pa, x0, acc0, 0, 0, 0);
        acc1 = __builtin_amdgcn_mfma_f32_16x16x32_bf16(pa, x1, acc1, 0, 0, 0);
        pa = npa; x0 = nx0; x1 = nx1;
    }
    acc0 = __builtin_amdgcn_mfma_f32_16x16x32_bf16(pa, x0, acc0, 0, 0, 0);
    acc1 = __builtin_amdgcn_mfma_f32_16x16x32_bf16(pa, x1, acc1, 0, 0, 0);

    // C/D layout: col = lane&15 (= d offset), row = (lane>>4)*4 + reg (= q)
    const int col = lane & 15;
    const int rb  = (lane >> 4) * 4;
    const int qi0 = (blockIdx.x * 8) & (L_ - 1);   // LOCAL q index (mask out batch)
    const size_t obase = (size_t)b * (L_ * D_) + (size_t)qi0 * D_;
    if (rb < 8) {   // lanes 0-31 hold valid q-rows 0-7
        if (isf32) {
            float* ob = (float*)out + obase;
            #pragma unroll
            for (int r = 0; r < 4; ++r) {
                ob[(size_t)(rb + r) * D_ + d0 + col]      = acc0[r];
                ob[(size_t)(rb + r) * D_ + d0 + 16 + col] = acc1[r];
            }
        } else {
            unsigned short* ob = (unsigned short*)out + obase;
            #pragma unroll
            for (int r = 0; r < 4; ++r) {
                ob[(size_t)(rb + r) * D_ + d0 + col]      = f2bf(acc0[r]);
                ob[(size_t)(rb + r) * D_ + d0 + 16 + col] = f2bf(acc1[r]);
            }
        }
    }
}

extern "C" void kernel_launch(void* const* d_in, const int* in_sizes, int n_in,
                              void* d_out, int out_size, void* d_ws, size_t ws_size,
                              hipStream_t stream) {
    const void* x  = d_in[0];   // [B,L,D]  dtype sniffed at runtime (fp32 expected)
    const void* Wt = d_in[1];   // [D,U]
    const void* Wx = d_in[2];   // [U,D]
    const void* bh = d_in[3];   // [U]
    const void* Wa = d_in[4];   // [U,1]
    // d_in[5] = ba: constant pre-softmax shift -> mathematically irrelevant.

    char* ws = (char*)d_ws;
    float*          P   = (float*)(ws + OFF_P);
    unsigned short* xT  = (unsigned short*)(ws + OFF_XT);
    float*          WV  = (float*)(ws + OFF_WV);

    proj_all<<<ROWS_ / 32, 256, 0, stream>>>(x, Wt, Wx, bh, Wa, P, xT, WV);
    alpha_pv<<<ROWS_ / 8, 512, 0, stream>>>(P, WV, x, xT, d_out);
}